// Round 1
// baseline (959.544 us; speedup 1.0000x reference)
//
#include <hip/hip_runtime.h>
#include <hip/hip_bf16.h>
#include <math.h>

// Problem constants
#define NTOK 8192
#define MDIM 4096
#define NEXP 64
#define DV   (MDIM / 4)   // float4 per row = 1024
#define CAPACITY 128.0f

// Output layout (all fp32): [indices 8192][capacity 1][locations 8192][gates 8192][num_experts 1]
#define OFF_IDX  0
#define OFF_CAP  8192
#define OFF_LOC  8193
#define OFF_GATE 16385
#define OFF_NE   24577

// ---------------------------------------------------------------------------
// Gate kernel: lane = expert. Each wave owns 8 tokens; block = 4 waves = 32
// tokens; grid = 256 blocks. K-loop in chunks of 64: W chunk staged in LDS
// (swizzled so the per-lane b128 read is a permuted-contiguous 1KB block),
// then copied to registers once per chunk; x is read through wave-uniform
// addresses -> scalar loads (SMEM pipe). Epilogue: in-wave argmax (first-max
// tie-break, matching np.argmax) + softmax denominator via shuffles.
// ---------------------------------------------------------------------------
__global__ __launch_bounds__(256) void gate_kernel(
    const float* __restrict__ x,
    const float* __restrict__ W,
    float* __restrict__ out)
{
    __shared__ float4 wbuf[16 * 64];   // [k4][col] swizzled, 16 KB

    const int tid  = threadIdx.x;
    const int lane = tid & 63;
    const int wv   = __builtin_amdgcn_readfirstlane(tid >> 6);  // force SGPR
    const int tok0 = blockIdx.x * 32 + wv * 8;

    const float4* __restrict__ W4 = (const float4*)W;
    const float4* __restrict__ x4 = (const float4*)x;

    float acc[8] = {0.f,0.f,0.f,0.f,0.f,0.f,0.f,0.f};

    for (int c = 0; c < MDIM / 64; ++c) {
        // --- stage W[0:64][c*64 .. c*64+63] into LDS, coalesced global reads
        #pragma unroll
        for (int j = 0; j < 4; ++j) {
            int i   = tid + j * 256;      // 0..1023
            int e   = i >> 4;             // row 0..63
            int k4g = i & 15;             // float4 within chunk 0..15
            float4 v = W4[e * DV + c * 16 + k4g];
            wbuf[k4g * 64 + (e ^ (k4g << 2))] = v;   // xor-swizzle
        }
        __syncthreads();

        // --- my expert row chunk -> registers (permuted-contiguous b128s)
        float4 wreg[16];
        #pragma unroll
        for (int k4 = 0; k4 < 16; ++k4)
            wreg[k4] = wbuf[k4 * 64 + (lane ^ (k4 << 2))];

        // --- accumulate 8 tokens; x addresses are wave-uniform => s_load
        #pragma unroll
        for (int t = 0; t < 8; ++t) {
            const float4* __restrict__ xrow = x4 + (size_t)(tok0 + t) * DV + c * 16;
            float px = 0.f, py = 0.f, pz = 0.f, pw = 0.f;
            #pragma unroll
            for (int k4 = 0; k4 < 16; ++k4) {
                float4 xv = xrow[k4];
                px = fmaf(xv.x, wreg[k4].x, px);
                py = fmaf(xv.y, wreg[k4].y, py);
                pz = fmaf(xv.z, wreg[k4].z, pz);
                pw = fmaf(xv.w, wreg[k4].w, pw);
            }
            acc[t] += (px + py) + (pz + pw);
        }
        __syncthreads();
    }

    // --- epilogue: per-token wave reduction (lane e holds logit[t][e])
    for (int t = 0; t < 8; ++t) {
        float m  = acc[t];
        int   am = lane;
        #pragma unroll
        for (int off = 32; off >= 1; off >>= 1) {
            float om = __shfl_xor(m, off, 64);
            int   oa = __shfl_xor(am, off, 64);
            if (om > m || (om == m && oa < am)) { m = om; am = oa; }
        }
        float ex = expf(acc[t] - m);
        #pragma unroll
        for (int off = 32; off >= 1; off >>= 1)
            ex += __shfl_xor(ex, off, 64);

        if (lane == 0) {
            int s = tok0 + t;
            out[OFF_IDX  + s] = (float)am;   // argmax logit == m, gate = 1/sum
            out[OFF_GATE + s] = 1.0f / ex;
        }
    }
}

// ---------------------------------------------------------------------------
// Locations kernel: loc[s] = #{ t < s : idx[t] == idx[s] }.
// Single block, 1024 threads (16 waves). Tokens in 128 chunks of 64 (one wave
// per chunk per round). Phase A: per-chunk per-expert counts via ballots
// (also capture each token's rank within its wave). Phase B: per-expert
// exclusive scan over the 128 chunks. Phase C: loc = chunk_base + rank.
// Also writes the two scalar outputs.
// ---------------------------------------------------------------------------
__global__ __launch_bounds__(1024) void loc_kernel(
    const float* __restrict__ idxf,   // = out + OFF_IDX
    float* __restrict__ out)
{
    __shared__ int cnt[128 * 64];     // [chunk][expert], 32 KB

    const int tid  = threadIdx.x;
    const int lane = tid & 63;
    const int w    = tid >> 6;        // 0..15

    int eS[8];
    int rk[8];
    const unsigned long long lt = (lane == 0) ? 0ull : ((~0ull) >> (64 - lane));

    for (int r = 0; r < 8; ++r) {
        int chunk = r * 16 + w;
        int s     = chunk * 64 + lane;
        int e     = (int)idxf[s];
        eS[r] = e;
        unsigned long long mymask = 0;
        for (int ee = 0; ee < 64; ++ee) {
            unsigned long long mb = __ballot(e == ee);
            if (lane == ee) mymask = mb;
            if (e == ee)    rk[r]  = (int)__popcll(mb & lt);
        }
        cnt[chunk * 64 + lane] = (int)__popcll(mymask);
    }
    __syncthreads();

    if (tid < 64) {   // per-expert exclusive scan over 128 chunks
        int run = 0;
        for (int c = 0; c < 128; ++c) {
            int v = cnt[c * 64 + tid];
            cnt[c * 64 + tid] = run;
            run += v;
        }
    }
    __syncthreads();

    for (int r = 0; r < 8; ++r) {
        int chunk = r * 16 + w;
        int s     = chunk * 64 + lane;
        out[OFF_LOC + s] = (float)(cnt[chunk * 64 + eS[r]] + rk[r]);
    }
    if (tid == 0) {
        out[OFF_CAP] = CAPACITY;
        out[OFF_NE]  = (float)NEXP;
    }
}

extern "C" void kernel_launch(void* const* d_in, const int* in_sizes, int n_in,
                              void* d_out, int out_size, void* d_ws, size_t ws_size,
                              hipStream_t stream)
{
    const float* x = (const float*)d_in[0];   // [8192, 4096] fp32
    const float* W = (const float*)d_in[1];   // [64, 4096] fp32
    float* out = (float*)d_out;               // 24578 fp32

    gate_kernel<<<NTOK / 32, 256, 0, stream>>>(x, W, out);
    loc_kernel<<<1, 1024, 0, stream>>>(out + OFF_IDX, out);
}

// Round 2
// 669.147 us; speedup vs baseline: 1.4340x; 1.4340x over previous
//
#include <hip/hip_runtime.h>
#include <math.h>

// Problem constants
#define NTOK 8192
#define MDIM 4096
#define NEXP 64
#define DV   (MDIM / 4)   // float4 per x/W row = 1024
#define CAPACITY 128.0f

// Output layout (all fp32): [indices 8192][capacity 1][locations 8192][gates 8192][num_experts 1]
#define OFF_IDX  0
#define OFF_CAP  8192
#define OFF_LOC  8193
#define OFF_GATE 16385
#define OFF_NE   24577

// ws layout in 4-byte units: [cnt 128*64][rk 8192][partials S*8192*64]
#define WS_CNT_OFF  0
#define WS_RK_OFF   (128 * 64)
#define WS_PART_OFF (128 * 64 + 8192)

// ---------------------------------------------------------------------------
// Split-K gate partial GEMM. grid = (256 token-groups, S slices), block 256.
// lane = expert; wave owns 8 tokens over a K-slice of 4096/S.
// W chunk (64 exp x 64 k) staged in LDS with swizzle unit = k4*64+((e+k4)&63):
// conflict-free for both the staging write (fixed e, k4 varies -> (e+k4)%8
// covers all 8 four-bank groups) and the per-lane read (fixed k4, consecutive
// e). Register sub-chunk of 8 float4 keeps VGPRs ~<=80 so wreg stays resident
// at 6 waves/SIMD.
// ---------------------------------------------------------------------------
template<int S>
__global__ __launch_bounds__(256, 6) void gate_partial(
    const float* __restrict__ x,
    const float* __restrict__ W,
    float* __restrict__ part)
{
    constexpr int C = 64 / S;            // 64-wide K-chunks per slice
    __shared__ float4 wbuf[16 * 64];     // 16 KB

    const int tid   = threadIdx.x;
    const int lane  = tid & 63;
    const int wv    = __builtin_amdgcn_readfirstlane(tid >> 6);
    const int tok0  = blockIdx.x * 32 + wv * 8;
    const int slice = blockIdx.y;
    const int c0    = slice * C;

    const float4* __restrict__ W4 = (const float4*)W;
    const float4* __restrict__ x4 = (const float4*)x;

    float acc[8] = {0.f,0.f,0.f,0.f,0.f,0.f,0.f,0.f};

    for (int c = c0; c < c0 + C; ++c) {
        // stage W[0:64][c*64 .. +63]: coalesced global (16 consecutive float4
        // per expert row), swizzled LDS write
        #pragma unroll
        for (int j = 0; j < 4; ++j) {
            int i  = tid + j * 256;      // 0..1023
            int e  = i >> 4;
            int k4 = i & 15;
            wbuf[k4 * 64 + ((e + k4) & 63)] = W4[e * DV + c * 16 + k4];
        }
        __syncthreads();

        #pragma unroll
        for (int h = 0; h < 2; ++h) {
            float4 wreg[8];
            #pragma unroll
            for (int r = 0; r < 8; ++r) {
                int k4 = h * 8 + r;
                wreg[r] = wbuf[k4 * 64 + ((lane + k4) & 63)];
            }
            #pragma unroll
            for (int t = 0; t < 8; ++t) {
                const float4* __restrict__ xrow =
                    x4 + (size_t)(tok0 + t) * DV + c * 16 + h * 8;
                float p0 = 0.f, p1 = 0.f, p2 = 0.f, p3 = 0.f;
                #pragma unroll
                for (int r = 0; r < 8; ++r) {
                    float4 xv = xrow[r];
                    p0 = fmaf(xv.x, wreg[r].x, p0);
                    p1 = fmaf(xv.y, wreg[r].y, p1);
                    p2 = fmaf(xv.z, wreg[r].z, p2);
                    p3 = fmaf(xv.w, wreg[r].w, p3);
                }
                acc[t] += (p0 + p1) + (p2 + p3);
            }
        }
        __syncthreads();
    }

    #pragma unroll
    for (int t = 0; t < 8; ++t)
        part[((size_t)slice * NTOK + tok0 + t) * 64 + lane] = acc[t];
}

// ---------------------------------------------------------------------------
// Reduce partials (deterministic order) + argmax/softmax epilogue.
// grid 512, block 256; wave owns 4 tokens, lane = expert.
// ---------------------------------------------------------------------------
template<int S>
__global__ __launch_bounds__(256) void reduce_kernel(
    const float* __restrict__ part,
    float* __restrict__ out)
{
    const int tid  = threadIdx.x;
    const int lane = tid & 63;
    const int wv   = tid >> 6;
    const int tok0 = blockIdx.x * 16 + wv * 4;

    for (int t = 0; t < 4; ++t) {
        const int tok = tok0 + t;
        float a = 0.f;
        #pragma unroll
        for (int s = 0; s < S; ++s)
            a += part[((size_t)s * NTOK + tok) * 64 + lane];

        float m  = a;
        int   am = lane;
        #pragma unroll
        for (int off = 32; off >= 1; off >>= 1) {
            float om = __shfl_xor(m, off, 64);
            int   oa = __shfl_xor(am, off, 64);
            if (om > m || (om == m && oa < am)) { m = om; am = oa; }
        }
        float ex = expf(a - m);
        #pragma unroll
        for (int off = 32; off >= 1; off >>= 1)
            ex += __shfl_xor(ex, off, 64);

        if (lane == 0) {
            out[OFF_IDX  + tok] = (float)am;   // logit at argmax == m
            out[OFF_GATE + tok] = 1.0f / ex;
        }
    }
}

// ---------------------------------------------------------------------------
// locations1_s = rank of token among same-expert tokens in token order.
// Phase 1: 128 blocks x 64 (one 64-token chunk per block): ballot histogram
// -> cnt[chunk][e], per-token in-chunk rank -> rk[s].
// ---------------------------------------------------------------------------
__global__ __launch_bounds__(64) void loc_count(
    const float* __restrict__ idxf,
    int* __restrict__ cnt,
    int* __restrict__ rk)
{
    const int chunk = blockIdx.x;
    const int lane  = threadIdx.x;
    const int s     = chunk * 64 + lane;
    const int e     = (int)idxf[s];
    const unsigned long long lt =
        (lane == 0) ? 0ull : ((~0ull) >> (64 - lane));

    unsigned long long mymask = 0;
    int myrk = 0;
    for (int ee = 0; ee < 64; ++ee) {
        unsigned long long mb = __ballot(e == ee);
        if (lane == ee) mymask = mb;
        if (e == ee)    myrk   = (int)__popcll(mb & lt);
    }
    cnt[chunk * 64 + lane] = (int)__popcll(mymask);
    rk[s] = myrk;
}

// Phase 2: one wave; lane = expert; exclusive scan over 128 chunks (batched
// loads so the 8 global reads per batch pipeline).
__global__ __launch_bounds__(64) void loc_scan(int* __restrict__ cnt)
{
    const int lane = threadIdx.x;
    int run = 0;
    for (int c0 = 0; c0 < 128; c0 += 8) {
        int v[8];
        #pragma unroll
        for (int j = 0; j < 8; ++j) v[j] = cnt[(c0 + j) * 64 + lane];
        #pragma unroll
        for (int j = 0; j < 8; ++j) { cnt[(c0 + j) * 64 + lane] = run; run += v[j]; }
    }
}

// Phase 3: loc[s] = chunk_base + in-chunk rank; also the two scalars.
__global__ __launch_bounds__(256) void loc_final(
    const float* __restrict__ idxf,
    const int* __restrict__ cnt,
    const int* __restrict__ rk,
    float* __restrict__ out)
{
    const int s = blockIdx.x * 256 + threadIdx.x;
    const int e = (int)idxf[s];
    out[OFF_LOC + s] = (float)(cnt[(s >> 6) * 64 + e] + rk[s]);
    if (s == 0) {
        out[OFF_CAP] = CAPACITY;
        out[OFF_NE]  = (float)NEXP;
    }
}

extern "C" void kernel_launch(void* const* d_in, const int* in_sizes, int n_in,
                              void* d_out, int out_size, void* d_ws, size_t ws_size,
                              hipStream_t stream)
{
    const float* x = (const float*)d_in[0];   // [8192, 4096] fp32
    const float* W = (const float*)d_in[1];   // [64, 4096] fp32
    float* out = (float*)d_out;               // 24578 fp32

    int*   cnt  = (int*)d_ws + WS_CNT_OFF;
    int*   rk   = (int*)d_ws + WS_RK_OFF;
    float* part = (float*)d_ws + WS_PART_OFF;

    const size_t base = (size_t)WS_PART_OFF * 4;
    const size_t per_slice = (size_t)NTOK * 64 * 4;   // 2 MB

    if (ws_size >= base + 8 * per_slice) {
        gate_partial<8><<<dim3(256, 8), 256, 0, stream>>>(x, W, part);
        reduce_kernel<8><<<512, 256, 0, stream>>>(part, out);
    } else if (ws_size >= base + 4 * per_slice) {
        gate_partial<4><<<dim3(256, 4), 256, 0, stream>>>(x, W, part);
        reduce_kernel<4><<<512, 256, 0, stream>>>(part, out);
    } else if (ws_size >= base + 2 * per_slice) {
        gate_partial<2><<<dim3(256, 2), 256, 0, stream>>>(x, W, part);
        reduce_kernel<2><<<512, 256, 0, stream>>>(part, out);
    } else {
        gate_partial<1><<<dim3(256, 1), 256, 0, stream>>>(x, W, part);
        reduce_kernel<1><<<512, 256, 0, stream>>>(part, out);
    }

    loc_count<<<128, 64, 0, stream>>>(out + OFF_IDX, cnt, rk);
    loc_scan<<<1, 64, 0, stream>>>(cnt);
    loc_final<<<32, 256, 0, stream>>>(out + OFF_IDX, cnt, rk, out);
}

// Round 3
// 440.142 us; speedup vs baseline: 2.1801x; 1.5203x over previous
//
#include <hip/hip_runtime.h>
#include <math.h>

// Problem constants
#define NTOK 8192
#define MDIM 4096
#define NEXP 64
#define DV   (MDIM / 4)   // float4 per x/W row = 1024
#define CAPACITY 128.0f

// Output layout (all fp32): [indices 8192][capacity 1][locations 8192][gates 8192][num_experts 1]
#define OFF_IDX  0
#define OFF_CAP  8192
#define OFF_LOC  8193
#define OFF_GATE 16385
#define OFF_NE   24577

// ws layout in 4-byte units: [cnt 128*64][rk 8192][partials S*8192*64]
#define WS_CNT_OFF  0
#define WS_RK_OFF   (128 * 64)
#define WS_PART_OFF (128 * 64 + 8192)

// ---------------------------------------------------------------------------
// Split-K gate partial GEMM. grid = (256 token-groups, S slices), block 256.
// lane = expert; wave owns 8 tokens over a K-slice of 4096/S.
//
// R3 change vs R2: launch_bounds min-waves 6 -> 3 (~168 VGPR budget; the
// (256,6)=40-VGPR build spilled its whole working set to scratch -> 350 MB
// of scratch WRITE traffic) and an explicit 2-stage x pipeline so pressure
// is bounded: w4[8]=32 + xv двойной buffer 64 + acc 8 + addr ~15 ~= 120 VGPR.
// W swizzle unit = k4*64+((e+k4)&63): measured 0 bank conflicts in R2 — kept.
// ---------------------------------------------------------------------------
template<int S>
__global__ __launch_bounds__(256, 3) void gate_partial(
    const float* __restrict__ x,
    const float* __restrict__ W,
    float* __restrict__ part)
{
    constexpr int C = 64 / S;            // 64-wide K-chunks per slice
    __shared__ float4 wbuf[16 * 64];     // 16 KB

    const int tid   = threadIdx.x;
    const int lane  = tid & 63;
    const int wv    = __builtin_amdgcn_readfirstlane(tid >> 6);
    const int tok0  = blockIdx.x * 32 + wv * 8;
    const int slice = blockIdx.y;
    const int c0    = slice * C;

    const float4* __restrict__ W4 = (const float4*)W;
    const float4* __restrict__ x4 = (const float4*)x;

    float acc[8] = {0.f,0.f,0.f,0.f,0.f,0.f,0.f,0.f};

    for (int c = c0; c < c0 + C; ++c) {
        // stage W[0:64][c*64 .. +63]: coalesced global (16 consecutive float4
        // per expert row), swizzled LDS write (conflict-free, measured)
        #pragma unroll
        for (int j = 0; j < 4; ++j) {
            int i  = tid + j * 256;      // 0..1023
            int e  = i >> 4;
            int k4 = i & 15;
            wbuf[k4 * 64 + ((e + k4) & 63)] = W4[e * DV + c * 16 + k4];
        }
        __syncthreads();

        #pragma unroll
        for (int h = 0; h < 2; ++h) {
            // my expert's half-chunk of W -> 8 float4 regs
            float4 w4[8];
            #pragma unroll
            for (int r = 0; r < 8; ++r) {
                int k4 = h * 8 + r;
                w4[r] = wbuf[k4 * 64 + ((lane + k4) & 63)];
            }

            const float4* __restrict__ xbase = x4 + (size_t)tok0 * DV + c * 16 + h * 8;

            // 2-stage pipeline over the 8 tokens: load t+1 while fma'ing t
            float4 xv0[8], xv1[8];
            #pragma unroll
            for (int r = 0; r < 8; ++r) xv0[r] = xbase[r];

            #pragma unroll
            for (int t = 0; t < 8; ++t) {
                if (t < 7) {
                    const float4* __restrict__ xn = xbase + (size_t)(t + 1) * DV;
                    #pragma unroll
                    for (int r = 0; r < 8; ++r) xv1[r] = xn[r];
                }
                float p0 = 0.f, p1 = 0.f, p2 = 0.f, p3 = 0.f;
                #pragma unroll
                for (int r = 0; r < 8; ++r) {
                    p0 = fmaf(xv0[r].x, w4[r].x, p0);
                    p1 = fmaf(xv0[r].y, w4[r].y, p1);
                    p2 = fmaf(xv0[r].z, w4[r].z, p2);
                    p3 = fmaf(xv0[r].w, w4[r].w, p3);
                }
                acc[t] += (p0 + p1) + (p2 + p3);
                #pragma unroll
                for (int r = 0; r < 8; ++r) xv0[r] = xv1[r];
            }
        }
        __syncthreads();
    }

    #pragma unroll
    for (int t = 0; t < 8; ++t)
        part[((size_t)slice * NTOK + tok0 + t) * 64 + lane] = acc[t];
}

// ---------------------------------------------------------------------------
// Reduce partials (deterministic order) + argmax/softmax epilogue.
// grid 512, block 256; wave owns 4 tokens, lane = expert.
// ---------------------------------------------------------------------------
template<int S>
__global__ __launch_bounds__(256) void reduce_kernel(
    const float* __restrict__ part,
    float* __restrict__ out)
{
    const int tid  = threadIdx.x;
    const int lane = tid & 63;
    const int wv   = tid >> 6;
    const int tok0 = blockIdx.x * 16 + wv * 4;

    for (int t = 0; t < 4; ++t) {
        const int tok = tok0 + t;
        float a = 0.f;
        #pragma unroll
        for (int s = 0; s < S; ++s)
            a += part[((size_t)s * NTOK + tok) * 64 + lane];

        float m  = a;
        int   am = lane;
        #pragma unroll
        for (int off = 32; off >= 1; off >>= 1) {
            float om = __shfl_xor(m, off, 64);
            int   oa = __shfl_xor(am, off, 64);
            if (om > m || (om == m && oa < am)) { m = om; am = oa; }
        }
        float ex = expf(a - m);
        #pragma unroll
        for (int off = 32; off >= 1; off >>= 1)
            ex += __shfl_xor(ex, off, 64);

        if (lane == 0) {
            out[OFF_IDX  + tok] = (float)am;   // logit at argmax == m
            out[OFF_GATE + tok] = 1.0f / ex;
        }
    }
}

// ---------------------------------------------------------------------------
// locations1_s = rank of token among same-expert tokens in token order.
// Phase 1: 128 blocks x 64: ballot histogram -> cnt[chunk][e], in-chunk rank.
// ---------------------------------------------------------------------------
__global__ __launch_bounds__(64) void loc_count(
    const float* __restrict__ idxf,
    int* __restrict__ cnt,
    int* __restrict__ rk)
{
    const int chunk = blockIdx.x;
    const int lane  = threadIdx.x;
    const int s     = chunk * 64 + lane;
    const int e     = (int)idxf[s];
    const unsigned long long lt =
        (lane == 0) ? 0ull : ((~0ull) >> (64 - lane));

    unsigned long long mymask = 0;
    int myrk = 0;
    for (int ee = 0; ee < 64; ++ee) {
        unsigned long long mb = __ballot(e == ee);
        if (lane == ee) mymask = mb;
        if (e == ee)    myrk   = (int)__popcll(mb & lt);
    }
    cnt[chunk * 64 + lane] = (int)__popcll(mymask);
    rk[s] = myrk;
}

// Phase 2: one wave; lane = expert; exclusive scan over 128 chunks.
__global__ __launch_bounds__(64) void loc_scan(int* __restrict__ cnt)
{
    const int lane = threadIdx.x;
    int run = 0;
    for (int c0 = 0; c0 < 128; c0 += 8) {
        int v[8];
        #pragma unroll
        for (int j = 0; j < 8; ++j) v[j] = cnt[(c0 + j) * 64 + lane];
        #pragma unroll
        for (int j = 0; j < 8; ++j) { cnt[(c0 + j) * 64 + lane] = run; run += v[j]; }
    }
}

// Phase 3: loc[s] = chunk_base + in-chunk rank; also the two scalars.
__global__ __launch_bounds__(256) void loc_final(
    const float* __restrict__ idxf,
    const int* __restrict__ cnt,
    const int* __restrict__ rk,
    float* __restrict__ out)
{
    const int s = blockIdx.x * 256 + threadIdx.x;
    const int e = (int)idxf[s];
    out[OFF_LOC + s] = (float)(cnt[(s >> 6) * 64 + e] + rk[s]);
    if (s == 0) {
        out[OFF_CAP] = CAPACITY;
        out[OFF_NE]  = (float)NEXP;
    }
}

extern "C" void kernel_launch(void* const* d_in, const int* in_sizes, int n_in,
                              void* d_out, int out_size, void* d_ws, size_t ws_size,
                              hipStream_t stream)
{
    const float* x = (const float*)d_in[0];   // [8192, 4096] fp32
    const float* W = (const float*)d_in[1];   // [64, 4096] fp32
    float* out = (float*)d_out;               // 24578 fp32

    int*   cnt  = (int*)d_ws + WS_CNT_OFF;
    int*   rk   = (int*)d_ws + WS_RK_OFF;
    float* part = (float*)d_ws + WS_PART_OFF;

    const size_t base = (size_t)WS_PART_OFF * 4;
    const size_t per_slice = (size_t)NTOK * 64 * 4;   // 2 MB

    if (ws_size >= base + 8 * per_slice) {
        gate_partial<8><<<dim3(256, 8), 256, 0, stream>>>(x, W, part);
        reduce_kernel<8><<<512, 256, 0, stream>>>(part, out);
    } else if (ws_size >= base + 4 * per_slice) {
        gate_partial<4><<<dim3(256, 4), 256, 0, stream>>>(x, W, part);
        reduce_kernel<4><<<512, 256, 0, stream>>>(part, out);
    } else if (ws_size >= base + 2 * per_slice) {
        gate_partial<2><<<dim3(256, 2), 256, 0, stream>>>(x, W, part);
        reduce_kernel<2><<<512, 256, 0, stream>>>(part, out);
    } else {
        gate_partial<1><<<dim3(256, 1), 256, 0, stream>>>(x, W, part);
        reduce_kernel<1><<<512, 256, 0, stream>>>(part, out);
    }

    loc_count<<<128, 64, 0, stream>>>(out + OFF_IDX, cnt, rk);
    loc_scan<<<1, 64, 0, stream>>>(cnt);
    loc_final<<<32, 256, 0, stream>>>(out + OFF_IDX, cnt, rk, out);
}

// Round 4
// 294.057 us; speedup vs baseline: 3.2631x; 1.4968x over previous
//
#include <hip/hip_runtime.h>
#include <math.h>

// Problem constants
#define NTOK 8192
#define MDIM 4096
#define NEXP 64
#define DV   (MDIM / 4)   // float4 per x/W row = 1024
#define CAPACITY 128.0f

// Output layout (all fp32): [indices 8192][capacity 1][locations 8192][gates 8192][num_experts 1]
#define OFF_IDX  0
#define OFF_CAP  8192
#define OFF_LOC  8193
#define OFF_GATE 16385
#define OFF_NE   24577

// ws layout in 4-byte units: [cnt 128*64? -> 8192][rk 8192][partials S*8192*64]
#define WS_CNT_OFF  0
#define WS_RK_OFF   8192
#define WS_PART_OFF (8192 + 8192)

// ---------------------------------------------------------------------------
// Gate partial GEMM, R4 structure:
//  - block = 256 thr = 4 waves; wave = 16 tokens; block = 64 tokens.
//  - grid = (128 token-groups, S K-slices). K-chunk = 64 (16 float4).
//  - x tile (64 tok x 64 K = 16 KB) staged into LDS via global_load_lds
//    width=16 (async, no VGPR round trip), double-buffered -> 16 KB in
//    flight per block covers HBM latency (R3 was 256 B/wave => 284 us).
//  - compute waves read x as uniform-address ds_read_b128 broadcasts.
//  - W (lane = expert) read directly from global per-lane; the 16 KB chunk
//    is shared by all 4 waves -> L1-resident. No W LDS staging, no swizzle.
//  - 4 independent FMA chains per token (p0..p3) to cover v_fma latency.
// ---------------------------------------------------------------------------
template<int S>
__global__ __launch_bounds__(256, 3) void gate_partial(
    const float* __restrict__ x,
    const float* __restrict__ W,
    float* __restrict__ part)
{
    constexpr int C = 64 / S;              // 64-wide K-chunks per slice
    __shared__ float4 xbuf[2][64 * 16];    // [buf][tok_rel*16 + k4], 2 x 16 KB

    const int tid   = threadIdx.x;
    const int lane  = tid & 63;
    const int wv    = __builtin_amdgcn_readfirstlane(tid >> 6);  // 0..3
    const int tok0  = blockIdx.x * 64;
    const int trel0 = wv * 16;
    const int slice = blockIdx.y;
    const int c0    = slice * C;

    const float4* __restrict__ W4 = (const float4*)W;
    const float4* __restrict__ x4 = (const float4*)x;

    // ---- async stage of one 64-tok x 64-K tile into xbuf[b] for chunk c
    auto stage = [&](int c, int b) {
        #pragma unroll
        for (int j = 0; j < 4; ++j) {
            int ii   = j * 256 + wv * 64 + lane;   // 0..1023
            int trel = ii >> 4;
            int k4   = ii & 15;
            const float4* g = x4 + (size_t)(tok0 + trel) * DV + c * 16 + k4;
            // LDS operand must be wave-uniform; HW scatters lane l to +16*l
            float4* l = &xbuf[b][j * 256 + wv * 64];
            __builtin_amdgcn_global_load_lds(
                (const __attribute__((address_space(1))) void*)g,
                (__attribute__((address_space(3))) void*)l, 16, 0, 0);
        }
    };

    float acc[16];
    #pragma unroll
    for (int t = 0; t < 16; ++t) acc[t] = 0.f;

    stage(c0, 0);
    __syncthreads();

    for (int ci = 0; ci < C; ++ci) {
        const int c   = c0 + ci;
        const int cur = ci & 1;
        if (ci + 1 < C) stage(c + 1, cur ^ 1);

        // W chunk for my expert row -> 16 float4 regs (global, L1-hot)
        float4 w4[16];
        #pragma unroll
        for (int k4 = 0; k4 < 16; ++k4)
            w4[k4] = W4[(size_t)lane * DV + c * 16 + k4];

        #pragma unroll
        for (int t = 0; t < 16; ++t) {
            const float4* __restrict__ xp = &xbuf[cur][(trel0 + t) * 16];
            float p0 = 0.f, p1 = 0.f, p2 = 0.f, p3 = 0.f;
            #pragma unroll
            for (int g = 0; g < 4; ++g) {
                float4 xv[4];
                #pragma unroll
                for (int r = 0; r < 4; ++r) xv[r] = xp[g * 4 + r];  // broadcast
                #pragma unroll
                for (int r = 0; r < 4; ++r) {
                    p0 = fmaf(xv[r].x, w4[g * 4 + r].x, p0);
                    p1 = fmaf(xv[r].y, w4[g * 4 + r].y, p1);
                    p2 = fmaf(xv[r].z, w4[g * 4 + r].z, p2);
                    p3 = fmaf(xv[r].w, w4[g * 4 + r].w, p3);
                }
            }
            acc[t] += (p0 + p1) + (p2 + p3);
        }
        __syncthreads();   // drains next stage (covered by ~2.3k cyc compute)
    }

    #pragma unroll
    for (int t = 0; t < 16; ++t)
        part[((size_t)slice * NTOK + tok0 + trel0 + t) * 64 + lane] = acc[t];
}

// ---------------------------------------------------------------------------
// Fused reduce + argmax/softmax + per-chunk histogram/rank.
// grid 128 blocks (one per 64-token chunk), block 256 = 4 waves.
// Phase 1: lane l -> token trel = wv*16 + (l>>2), quarter q = l&3 (16 experts
//   per lane). Coalesced float4 partial loads, deterministic s-order sum.
//   Argmax/softmax via 2-step shuffle over the 4 lanes of each token.
// Phase 2: wave 0 ballots the block's 64 indices -> cnt[chunk][e], rk[s].
// ---------------------------------------------------------------------------
template<int S>
__global__ __launch_bounds__(256) void reduce_count(
    const float* __restrict__ part,
    float* __restrict__ out,
    int* __restrict__ cnt,
    int* __restrict__ rk)
{
    __shared__ int eidx[64];

    const int tid  = threadIdx.x;
    const int lane = tid & 63;
    const int wv   = tid >> 6;
    const int tok0 = blockIdx.x * 64;
    const int trel = wv * 16 + (lane >> 2);
    const int tok  = tok0 + trel;
    const int q    = lane & 3;

    const float4* __restrict__ p4 = (const float4*)part;

    float4 a[4];
    #pragma unroll
    for (int r = 0; r < 4; ++r) a[r] = make_float4(0.f, 0.f, 0.f, 0.f);
    for (int s = 0; s < S; ++s) {
        #pragma unroll
        for (int r = 0; r < 4; ++r) {
            float4 v = p4[((size_t)s * NTOK + tok) * 16 + q * 4 + r];
            a[r].x += v.x; a[r].y += v.y; a[r].z += v.z; a[r].w += v.w;
        }
    }

    float vals[16];
    #pragma unroll
    for (int r = 0; r < 4; ++r) {
        vals[r * 4 + 0] = a[r].x; vals[r * 4 + 1] = a[r].y;
        vals[r * 4 + 2] = a[r].z; vals[r * 4 + 3] = a[r].w;
    }

    float bm = vals[0];
    int   be = q * 16;
    #pragma unroll
    for (int j = 1; j < 16; ++j)
        if (vals[j] > bm) { bm = vals[j]; be = q * 16 + j; }
    #pragma unroll
    for (int off = 1; off <= 2; off <<= 1) {
        float om = __shfl_xor(bm, off, 64);
        int   oe = __shfl_xor(be, off, 64);
        if (om > bm || (om == bm && oe < be)) { bm = om; be = oe; }
    }

    float es = 0.f;
    #pragma unroll
    for (int j = 0; j < 16; ++j) es += expf(vals[j] - bm);
    #pragma unroll
    for (int off = 1; off <= 2; off <<= 1)
        es += __shfl_xor(es, off, 64);

    if (q == 0) {
        out[OFF_IDX  + tok] = (float)be;
        out[OFF_GATE + tok] = 1.0f / es;
        eidx[trel] = be;
    }
    __syncthreads();

    if (tid < 64) {
        const int e = eidx[tid];
        const unsigned long long lt =
            (tid == 0) ? 0ull : ((~0ull) >> (64 - tid));
        unsigned long long mymask = 0;
        int myrk = 0;
        for (int ee = 0; ee < 64; ++ee) {
            unsigned long long mb = __ballot(e == ee);
            if (tid == ee) mymask = mb;
            if (e == ee)   myrk   = (int)__popcll(mb & lt);
        }
        cnt[blockIdx.x * 64 + tid] = (int)__popcll(mymask);
        rk[tok0 + tid] = myrk;
    }
    if (tid == 0 && blockIdx.x == 0) {
        out[OFF_CAP] = CAPACITY;
        out[OFF_NE]  = (float)NEXP;
    }
}

// ---------------------------------------------------------------------------
// Fused scan + final: one block, 1024 threads (16 waves). Hierarchical
// per-expert exclusive scan over 128 chunks entirely in LDS, then emit
// loc[s] = scanned_base[chunk][e] + rk[s].
// ---------------------------------------------------------------------------
__global__ __launch_bounds__(1024) void scan_final(
    const float* __restrict__ idxf,
    const int* __restrict__ cnt,
    const int* __restrict__ rk,
    float* __restrict__ out)
{
    __shared__ int lcnt[128 * 64];   // 32 KB
    __shared__ int wtot[16 * 64];    // 4 KB

    const int tid  = threadIdx.x;
    const int lane = tid & 63;
    const int w    = tid >> 6;       // 0..15

    #pragma unroll
    for (int j = 0; j < 8; ++j) lcnt[j * 1024 + tid] = cnt[j * 1024 + tid];
    __syncthreads();

    // wave w: chunks 8w..8w+7, lane = expert
    {
        int sum = 0;
        #pragma unroll
        for (int j = 0; j < 8; ++j) sum += lcnt[(w * 8 + j) * 64 + lane];
        wtot[w * 64 + lane] = sum;
    }
    __syncthreads();

    if (tid < 64) {  // serial scan over the 16 wave-totals per expert
        int run = 0;
        #pragma unroll
        for (int w2 = 0; w2 < 16; ++w2) {
            int t = wtot[w2 * 64 + tid];
            wtot[w2 * 64 + tid] = run;
            run += t;
        }
    }
    __syncthreads();

    {
        int run = wtot[w * 64 + lane];
        #pragma unroll
        for (int j = 0; j < 8; ++j) {
            int c = w * 8 + j;
            int v = lcnt[c * 64 + lane];
            lcnt[c * 64 + lane] = run;
            run += v;
        }
    }
    __syncthreads();

    #pragma unroll
    for (int j = 0; j < 8; ++j) {
        int s = j * 1024 + tid;
        int e = (int)idxf[s];
        out[OFF_LOC + s] = (float)(lcnt[(s >> 6) * 64 + e] + rk[s]);
    }
}

extern "C" void kernel_launch(void* const* d_in, const int* in_sizes, int n_in,
                              void* d_out, int out_size, void* d_ws, size_t ws_size,
                              hipStream_t stream)
{
    const float* x = (const float*)d_in[0];   // [8192, 4096] fp32
    const float* W = (const float*)d_in[1];   // [64, 4096] fp32
    float* out = (float*)d_out;               // 24578 fp32

    int*   cnt  = (int*)d_ws + WS_CNT_OFF;
    int*   rk   = (int*)d_ws + WS_RK_OFF;
    float* part = (float*)d_ws + WS_PART_OFF;

    const size_t base = (size_t)WS_PART_OFF * 4;
    const size_t per_slice = (size_t)NTOK * 64 * 4;   // 2 MB

    if (ws_size >= base + 8 * per_slice) {
        gate_partial<8><<<dim3(128, 8), 256, 0, stream>>>(x, W, part);
        reduce_count<8><<<128, 256, 0, stream>>>(part, out, cnt, rk);
    } else if (ws_size >= base + 4 * per_slice) {
        gate_partial<4><<<dim3(128, 4), 256, 0, stream>>>(x, W, part);
        reduce_count<4><<<128, 256, 0, stream>>>(part, out, cnt, rk);
    } else if (ws_size >= base + 2 * per_slice) {
        gate_partial<2><<<dim3(128, 2), 256, 0, stream>>>(x, W, part);
        reduce_count<2><<<128, 256, 0, stream>>>(part, out, cnt, rk);
    } else {
        gate_partial<1><<<dim3(128, 1), 256, 0, stream>>>(x, W, part);
        reduce_count<1><<<128, 256, 0, stream>>>(part, out, cnt, rk);
    }

    scan_final<<<1, 1024, 0, stream>>>(out + OFF_IDX, cnt, rk, out);
}